// Round 10
// baseline (989.910 us; speedup 1.0000x reference)
//
#include <hip/hip_runtime.h>
#include <math.h>

#define BATCH 4
#define HH 512
#define WW 1024
#define NPIX (HH*WW)          // 524288 = 2^19
#define CCAP 196608           // compaction capacity per image (expected ~161.7k valid)
#define GX 64
#define GY 48
#define NCELL (GX*GY)         // 3072 cells, 0.0625 x 0.0625 over [-1,3]x[-1,2]
#define CELL 0.0625f
#define INVCELL 16.0f
#define SEGSZ 256             // pixels per argmax-cache segment
#define NSEGMAX (CCAP/SEGSZ)  // 768
#define DLCAP 1024            // dirty-segment list capacity
#define CKCAP 1024            // unified chunk queue capacity (worst ~600 dual)

// ---------------- XLA:CPU f32 math replicas (unchanged from passing rounds) ----
__device__ __forceinline__ float xla_tanhf(float x) {
  if (fabsf(x) < 0.0004f) return x;
  float xc = fminf(fmaxf(x, -7.90531110763549805f), 7.90531110763549805f);
  float x2 = __fmul_rn(xc, xc);
  float p = -2.76076847742355e-16f;
  p = fmaf(x2, p, 2.00018790482477e-13f);
  p = fmaf(x2, p, -8.60467152213735e-11f);
  p = fmaf(x2, p, 5.12229709037114e-08f);
  p = fmaf(x2, p, 1.48572235717979e-05f);
  p = fmaf(x2, p, 6.37261928875436e-04f);
  p = fmaf(x2, p, 4.89352455891786e-03f);
  p = __fmul_rn(xc, p);
  float q = fmaf(x2, 1.19825839466702e-06f, 1.18534705686654e-04f);
  q = fmaf(x2, q, 2.26843463243900e-03f);
  q = fmaf(x2, q, 4.89352518554385e-03f);
  return __fdiv_rn(p, q);
}

__device__ __forceinline__ float xla_expf(float x) {
  float xc = fminf(fmaxf(x, -87.3365478515625f), 88.72283935546875f);
  float m = floorf(fmaf(xc, 1.44269504088896341f, 0.5f));
  float r = fmaf(m, -0.693359375f, xc);
  r = fmaf(m, 2.12194440e-4f, r);
  float r2 = __fmul_rn(r, r);
  float p = 1.9875691500e-4f;
  p = fmaf(p, r, 1.3981999507e-3f);
  p = fmaf(p, r, 8.3334519073e-3f);
  p = fmaf(p, r, 4.1665795894e-2f);
  p = fmaf(p, r, 1.6666665459e-1f);
  p = fmaf(p, r, 5.0000001201e-1f);
  float y = fmaf(r2, p, r);
  y = __fadd_rn(y, 1.0f);
  return ldexpf(y, (int)m);
}

__device__ __forceinline__ float xla_sigmoidf(float x) {
  return fmaf(0.5f, xla_tanhf(__fmul_rn(0.5f, x)), 0.5f);
}

// Proposal test — byte-identical decision logic to the passing kernels.
__device__ __forceinline__ bool prop_test(float2 e, float cx, float cy,
                                          float den0, float den1,
                                          float inv0, float inv1) {
  float d0 = __fsub_rn(e.x, cx), d1 = __fsub_rn(e.y, cy);
  float dd0 = __fmul_rn(d0, d0), dd1 = __fmul_rn(d1, d1);
  float zf = fmaf(dd0, inv0, __fmul_rn(dd1, inv1));
  if (zf < 0.6921472f) return true;
  if (zf <= 0.6941472f) {
    float t0 = __fdiv_rn(dd0, den0);
    float t1 = __fdiv_rn(dd1, den1);
    float z = __fadd_rn(t0, t1);
    return xla_expf(-z) > 0.5f;
  }
  return false;
}

__device__ __forceinline__ int cell_of_x(float ex) {
  int c = (int)((ex + 1.0f) * INVCELL);
  return min(max(c, 0), GX - 1);
}
__device__ __forceinline__ int cell_of_y(float ey) {
  int c = (int)((ey + 1.0f) * INVCELL);
  return min(max(c, 0), GY - 1);
}

// ---------------- kernels ----------------

__global__ __launch_bounds__(1024) void fill_kernel(int* out, int val, int n) {
  int i = blockIdx.x * 1024 + threadIdx.x;
  if (i < n) out[i] = val;
}

// pass A: zero output, LDS-aggregated histogram
__global__ __launch_bounds__(1024) void hist_kernel(const float* __restrict__ in,
                                                    int* __restrict__ out,
                                                    int* __restrict__ hist) {
  __shared__ int lh[NCELL];
  int tid = threadIdx.x;
  int gid = blockIdx.x * 1024 + tid;
  int b = gid >> 19;
  int p = gid & (NPIX - 1);
  for (int j = tid; j < NCELL; j += 1024) lh[j] = 0;
  __syncthreads();
  const float* base = in + (size_t)b * 5 * NPIX;
  float seed = base[(size_t)4 * NPIX + p];
  out[gid] = 0;
  if (seed > 0.5f) {
    float ox = base[p];
    float oy = base[(size_t)NPIX + p];
    int col = p & (WW - 1);
    int row = p >> 10;
    float gx = __fmul_rn((float)col, 2.0f / 1023.0f);
    float gy = __fmul_rn((float)row, 1.0f / 511.0f);
    float ex = __fadd_rn(xla_tanhf(ox), gx);
    float ey = __fadd_rn(xla_tanhf(oy), gy);
    atomicAdd(&lh[cell_of_y(ey) * GX + cell_of_x(ex)], 1);
  }
  __syncthreads();
  for (int j = tid; j < NCELL; j += 1024) {
    int c = lh[j];
    if (c) atomicAdd(&hist[b * NCELL + j], c);
  }
}

// pass B: exclusive scan of the cell counts per image
__global__ __launch_bounds__(1024) void scan_kernel(const int* __restrict__ hist,
                                                    int* __restrict__ off,
                                                    int* __restrict__ cursor) {
  __shared__ int s_c[NCELL];
  __shared__ int s_ps[1024];
  int b = blockIdx.x, t = threadIdx.x;
  const int* h = hist + b * NCELL;
  for (int i = t; i < NCELL; i += 1024) s_c[i] = h[i];
  __syncthreads();
  int a = s_c[3 * t], b2 = s_c[3 * t + 1], c2 = s_c[3 * t + 2];
  int th = a + b2 + c2;
  s_ps[t] = th;
  __syncthreads();
  for (int d = 1; d < 1024; d <<= 1) {
    int v = (t >= d) ? s_ps[t - d] : 0;
    __syncthreads();
    s_ps[t] += v;
    __syncthreads();
  }
  int excl = s_ps[t] - th;
  int* ob = off + b * (NCELL + 1);
  int* cb = cursor + b * NCELL;
  ob[3 * t] = excl;              cb[3 * t] = excl;
  ob[3 * t + 1] = excl + a;      cb[3 * t + 1] = excl + a;
  ob[3 * t + 2] = excl + a + b2; cb[3 * t + 2] = excl + a + b2;
  if (t == 1023) ob[NCELL] = s_ps[1023];
}

// pass C: LDS-aggregated scatter (within-cell order arbitrary; downstream is
// order-independent, tiebreak uses global pixel index)
__global__ __launch_bounds__(1024) void scatter_kernel(const float* __restrict__ in,
                                                       int* __restrict__ cursor,
                                                       float2* __restrict__ emb,
                                                       int2* __restrict__ pk) {
  __shared__ int lh[NCELL];
  __shared__ int lbase[NCELL];
  int tid = threadIdx.x;
  int gid = blockIdx.x * 1024 + tid;
  int b = gid >> 19;
  int p = gid & (NPIX - 1);
  for (int j = tid; j < NCELL; j += 1024) lh[j] = 0;
  __syncthreads();
  const float* base = in + (size_t)b * 5 * NPIX;
  float seed = base[(size_t)4 * NPIX + p];
  bool valid = seed > 0.5f;
  float ex = 0.0f, ey = 0.0f, smv = 0.0f;
  int cell = 0, sl = 0;
  if (valid) {
    float ox = base[p];
    float oy = base[(size_t)NPIX + p];
    int col = p & (WW - 1);
    int row = p >> 10;
    float gx = __fmul_rn((float)col, 2.0f / 1023.0f);
    float gy = __fmul_rn((float)row, 1.0f / 511.0f);
    ex = __fadd_rn(xla_tanhf(ox), gx);
    ey = __fadd_rn(xla_tanhf(oy), gy);
    smv = xla_sigmoidf(seed);
    cell = cell_of_y(ey) * GX + cell_of_x(ex);
    sl = atomicAdd(&lh[cell], 1);
  }
  __syncthreads();
  for (int j = tid; j < NCELL; j += 1024) {
    int c = lh[j];
    if (c) lbase[j] = atomicAdd(&cursor[b * NCELL + j], c);
  }
  __syncthreads();
  if (valid) {
    int slot = lbase[cell] + sl;
    if (slot < CCAP) {
      emb[(size_t)b * CCAP + slot] = make_float2(ex, ey);
      pk[(size_t)b * CCAP + slot]  = make_int2(__float_as_int(smv), p);
    }
  }
}

// Segment scan: (top key, top2 key, winner ci) per 256-px segment; winner lane
// writes aux=(cx,cy,den0,den1).
__device__ __forceinline__ void seg_rescan(int s, int V, int lane,
    const unsigned* s_uncl, const int2* __restrict__ pk,
    const float2* __restrict__ emb, const float* __restrict__ base,
    unsigned long long* s_segkey, unsigned long long* s_segkey2,
    int* s_segci, float4* s_segaux, bool checkAlive) {
  unsigned long long bk = 0ULL, bk2 = 0ULL; int bci = -1; int bpx = 0;
  #pragma unroll
  for (int j = 0; j < 4; ++j) {
    int i = (s << 8) + (j << 6) + lane;
    if (i < V) {
      bool alive = !checkAlive || ((s_uncl[i >> 5] >> (i & 31)) & 1u);
      if (alive) {
        int2 v = pk[i];
        unsigned long long k = ((unsigned long long)(unsigned)v.x << 32) | (unsigned)(~v.y);
        if (k > bk) { bk2 = bk; bk = k; bci = i; bpx = v.y; }
        else if (k > bk2) bk2 = k;
      }
    }
  }
  unsigned long long mk = bk, mk2 = bk2; int mci = bci;
  #pragma unroll
  for (int o = 1; o < 64; o <<= 1) {
    unsigned long long ok = __shfl_xor(mk, o);
    unsigned long long ok2 = __shfl_xor(mk2, o);
    int oci = __shfl_xor(mci, o);
    unsigned long long lo = (mk < ok) ? mk : ok;
    unsigned long long hi2 = (mk2 > ok2) ? mk2 : ok2;
    if (ok > mk) { mk = ok; mci = oci; }
    mk2 = (lo > hi2) ? lo : hi2;
  }
  if (lane == 0) { s_segkey[s] = mk; s_segkey2[s] = mk2; s_segci[s] = mci; }
  if (mk != 0ULL && bk == mk) {          // unique winner lane
    float2 e = emb[mci];
    float sxv = base[(size_t)2 * NPIX + bpx];
    float syv = base[(size_t)3 * NPIX + bpx];
    float d0 = __fmul_rn(2.0f, __fmul_rn(sxv, sxv));   // ref: 2.0 * s**2
    float d1 = __fmul_rn(2.0f, __fmul_rn(syv, syv));
    s_segaux[s] = make_float4(e.x, e.y, d0, d1);
  }
}

// One workgroup per image. 2 barriers per loop trip; a trip processes 1 or 2
// provably-commuting greedy iterations (dual-issue when proposal bboxes are
// disjoint, seg-runner-up < 2nd segment key, and ucount guard holds).
__global__ __launch_bounds__(1024) void cluster_kernel(const float* __restrict__ in,
                                                       int* __restrict__ out,
                                                       const float2* __restrict__ emb_all,
                                                       const int2* __restrict__ pk_all,
                                                       const int* __restrict__ off_g) {
  __shared__ unsigned int s_uncl[CCAP / 32];            // 24 KB
  __shared__ int s_off[NCELL + 1];                      // 12 KB
  __shared__ unsigned long long s_segkey[NSEGMAX];      // 6 KB
  __shared__ unsigned long long s_segkey2[NSEGMAX];     // 6 KB
  __shared__ int s_segci[NSEGMAX];                      // 3 KB
  __shared__ float4 s_segaux[NSEGMAX];                  // 12 KB
  __shared__ int s_dlist[DLCAP];                        // 4 KB
  __shared__ int4 s_ck4[CKCAP];                         // 16 KB
  __shared__ int s_pc[2][2];
  __shared__ int s_uc[2][2];
  __shared__ int s_nd[2];

  int b = blockIdx.x;
  int tid = threadIdx.x;
  int lane = tid & 63;
  int wid = tid >> 6;
  const int* offb = off_g + b * (NCELL + 1);
  int V = offb[NCELL];
  const float2* emb = emb_all + (size_t)b * CCAP;
  const int2*   pk  = pk_all  + (size_t)b * CCAP;
  int* outb = out + (size_t)b * NPIX;
  const float* base = in + (size_t)b * 5 * NPIX;

  if (V > CCAP) {   // capacity overflow marker
    for (int i = tid; i < NPIX; i += 1024) outb[i] = 1000000;
    return;
  }
  int NSEG = (V + SEGSZ - 1) >> 8;

  for (int i = tid; i <= NCELL; i += 1024) s_off[i] = offb[i];
  for (int w = tid; w < CCAP / 32; w += 1024) {
    int basebit = w << 5;
    unsigned m;
    if (basebit + 32 <= V)      m = 0xffffffffu;
    else if (basebit >= V)      m = 0u;
    else                        m = (1u << (V - basebit)) - 1u;
    s_uncl[w] = m;
  }
  if (tid < 2) { s_pc[tid][0] = 0; s_pc[tid][1] = 0; s_uc[tid][0] = 0; s_uc[tid][1] = 0; s_nd[tid] = 0; }
  __syncthreads();

  for (int s = wid; s < NSEG; s += 16)
    seg_rescan(s, V, lane, s_uncl, pk, emb, base, s_segkey, s_segkey2,
               s_segci, s_segaux, false);
  __syncthreads();

  int ucount = V, count = 1, guard = 0;
  int t = 0;
  while (ucount > 64 && guard++ <= CCAP) {
    int cur = t & 1, nxt = cur ^ 1;

    // ---- wave-redundant top-2-distinct-segment argmax ----
    unsigned long long lk = 0ULL, lk2 = 0ULL; int lsg = -1, lsg2 = -1;
    for (int s = lane; s < NSEG; s += 64) {
      unsigned long long v = s_segkey[s];
      if (v > lk) { lk2 = lk; lsg2 = lsg; lk = v; lsg = s; }
      else if (v > lk2) { lk2 = v; lsg2 = s; }
    }
    unsigned long long gk = lk, gk2 = lk2; int gsg = lsg, gsg2 = lsg2;
    #pragma unroll
    for (int o = 1; o < 64; o <<= 1) {
      unsigned long long ok = __shfl_xor(gk, o);
      unsigned long long ok2 = __shfl_xor(gk2, o);
      int osg = __shfl_xor(gsg, o);
      int osg2 = __shfl_xor(gsg2, o);
      if (ok > gk) {
        unsigned long long c = gk; int csg = gsg;
        gk = ok; gsg = osg;
        if (c >= ok2) { gk2 = c; gsg2 = csg; } else { gk2 = ok2; gsg2 = osg2; }
      } else if (ok > gk2) { gk2 = ok; gsg2 = osg; }
    }
    if (gk == 0ULL) break;
    float sm = __uint_as_float((unsigned)(gk >> 32));
    if (sm < 0.5f) break;              // ref's new_done (provably never fires)

    // ---- candidate A params ----
    float4 auxA = s_segaux[gsg];
    float cxA = auxA.x, cyA = auxA.y, den0A = auxA.z, den1A = auxA.w;
    float inv0A = 1.0f / den0A, inv1A = 1.0f / den1A;
    float rxA = sqrtf(__fmul_rn(den0A, 0.6971472f)) * 1.00001f;
    float ryA = sqrtf(__fmul_rn(den1A, 0.6971472f)) * 1.00001f;
    int r0A = cell_of_y(cyA - ryA), r1A = cell_of_y(cyA + ryA);
    int nrA = r1A - r0A + 1;

    // ---- speculation checks (geometry-free part) ----
    bool spec0 = false;
    float cxB = 0, cyB = 0, den0B = 1, den1B = 1, inv0B = 1, inv1B = 1;
    int r0B = 0, nrB = 0;
    if (gk2 != 0ULL) {
      float sm2 = __uint_as_float((unsigned)(gk2 >> 32));
      if (sm2 >= 0.5f && s_segkey2[gsg] < gk2) {
        float4 auxB = s_segaux[gsg2];
        cxB = auxB.x; cyB = auxB.y; den0B = auxB.z; den1B = auxB.w;
        float rxB = sqrtf(__fmul_rn(den0B, 0.6971472f)) * 1.00001f;
        float ryB = sqrtf(__fmul_rn(den1B, 0.6971472f)) * 1.00001f;
        if (fabsf(cxA - cxB) > rxA + rxB + 1e-3f ||
            fabsf(cyA - cyB) > ryA + ryB + 1e-3f) {
          spec0 = true;
          inv0B = 1.0f / den0B; inv1B = 1.0f / den1B;
          int r1B = cell_of_y(cyB + ryB);
          r0B = cell_of_y(cyB - ryB);
          nrB = r1B - r0B + 1;
        }
      }
    }

    // ---- per-lane row geometry: lanes 0..31 cand A, 32..63 cand B ----
    int candl = lane >> 5;
    int rr = lane & 31;
    int nrc = candl ? (spec0 ? nrB : 0) : nrA;
    int ckl = 0, rsl = 0, rel = 0, m0l = 0, m1l = 0;
    if (rr < nrc) {
      int r = (candl ? r0B : r0A) + rr;
      float CY = candl ? cyB : cyA;
      float CX = candl ? cxB : cxA;
      float D0 = candl ? den0B : den0A;
      float I1 = candl ? inv1B : inv1A;
      float ylo = fmaf((float)r, CELL, -1.0f);
      float dy = fmaxf(0.0f, fmaxf(ylo - CY, CY - (ylo + CELL))) * 0.999999f;
      float rem = 0.6971472f - dy * dy * I1;
      if (rem > 0.0f) {
        float dxm = sqrtf(D0 * rem) * 1.00001f;
        int c0 = cell_of_x(CX - dxm), c1 = cell_of_x(CX + dxm);
        int rbase = r * GX;
        rsl = s_off[rbase + c0]; rel = s_off[rbase + c1 + 1];
        m0l = rsl; m1l = rsl;
        float dyc = fmaxf(fabsf(ylo - CY), fabsf(ylo + CELL - CY)) + 1e-5f;
        float remI = 0.6920f - dyc * dyc * I1;
        if (remI > 0.0f) {
          float dxin = sqrtf(D0 * remI) * 0.9999f;
          int a  = (int)ceilf(fmaf(CX - dxin, INVCELL, INVCELL) + 1e-3f);
          int bb = (int)floorf(fmaf(CX + dxin, INVCELL, INVCELL) - 1e-3f) - 1;
          a = max(a, c0); bb = min(bb, c1);
          if (a <= bb) { m0l = s_off[rbase + a]; m1l = s_off[rbase + bb + 1]; }
        }
        ckl = (rel - rsl + 127) >> 7;
      }
    }
    // pxA = exact bbox-A pixel count (uc_A upper bound, for the while-cond guard)
    int pxl = (candl == 0) ? (rel - rsl) : 0;
    #pragma unroll
    for (int o = 1; o < 64; o <<= 1) pxl += __shfl_xor(pxl, o);
    bool dual = spec0 && (ucount > 64 + pxl);
    if (!dual && candl) ckl = 0;

    // prefix over 64 lanes -> unified queue positions; slice-write (pos%16==wid)
    int cum = ckl;
    #pragma unroll
    for (int o = 1; o < 64; o <<= 1) {
      int u = __shfl_up(cum, o);
      if (lane >= o) cum += u;
    }
    int nc = __shfl(cum, 63);
    int excl = cum - ckl;
    for (int k = 0; k < ckl; ++k) {
      int pos = excl + k;
      if ((pos & 15) == wid) {
        int i0 = rsl + (k << 7);
        s_ck4[pos] = make_int4(i0 | (candl << 24), min(i0 + 128, rel), m0l, m1l);
      }
    }

    // ---- pass 1: unified chunk queue, clears + counts per candidate ----
    int pcL0 = 0, ucL0 = 0, pcL1 = 0, ucL1 = 0;
    for (int c = wid; c < nc; c += 16) {
      int4 e = s_ck4[c];
      int cand = e.x >> 24;
      int i0 = e.x & 0xffffff;
      int hi = e.y, M0 = e.z, M1 = e.w;
      float CX = cand ? cxB : cxA;
      float CY = cand ? cyB : cyA;
      float D0 = cand ? den0B : den0A;
      float D1 = cand ? den1B : den1A;
      float I0 = cand ? inv0B : inv0A;
      float I1 = cand ? inv1B : inv1A;
      int i = i0 + lane, i2 = i + 64;
      bool p0, p1;
      if (i0 >= M0 && i0 + 128 <= M1) { p0 = i < hi; p1 = i2 < hi; }
      else {
        p0 = (i < hi) && ((i >= M0 && i < M1) ||
                          prop_test(emb[i], CX, CY, D0, D1, I0, I1));
        p1 = (i2 < hi) && ((i2 >= M0 && i2 < M1) ||
                           prop_test(emb[i2], CX, CY, D0, D1, I0, I1));
      }
      unsigned long long bm0 = __ballot(p0);
      unsigned long long bm1 = __ballot(p1);
      if ((bm0 | bm1) == 0ULL) continue;
      int off = i0 & 31;
      unsigned w = (unsigned)(i0 >> 5);
      unsigned bits = 0; unsigned tw = w;
      if (lane == 0)      { int x = (int)__popcll(bm0); if (cand) pcL1 += x; else pcL0 += x;
                            bits = (unsigned)(bm0 << off); tw = w; }
      else if (lane == 1) { bits = (unsigned)(bm0 >> (32 - off)); tw = w + 1; }
      else if (lane == 2) { if (off > 0) bits = (unsigned)(bm0 >> (64 - off)); tw = w + 2; }
      else if (lane == 3) { int x = (int)__popcll(bm1); if (cand) pcL1 += x; else pcL0 += x;
                            bits = (unsigned)(bm1 << off); tw = w + 2; }
      else if (lane == 4) { bits = (unsigned)(bm1 >> (32 - off)); tw = w + 3; }
      else if (lane == 5) { if (off > 0) bits = (unsigned)(bm1 >> (64 - off)); tw = w + 4; }
      if (bits) {
        unsigned old = atomicAnd(&s_uncl[tw], ~bits);
        unsigned remv = old & bits;
        if (remv) {
          int x = __popc(remv);
          if (cand) ucL1 += x; else ucL0 += x;
          int seg = (int)(tw >> 3);           // 256 px = 8 words
          int ciw = s_segci[seg];
          if ((ciw >> 5) == (int)tw && ((remv >> (ciw & 31)) & 1u)) {
            int pos = atomicAdd(&s_nd[cur], 1);
            if (pos < DLCAP) s_dlist[pos] = seg;
          }
        }
      }
    }
    #pragma unroll
    for (int o = 32; o > 0; o >>= 1) {
      pcL0 += __shfl_down(pcL0, o); ucL0 += __shfl_down(ucL0, o);
      pcL1 += __shfl_down(pcL1, o); ucL1 += __shfl_down(ucL1, o);
    }
    if (lane == 0) {
      if (pcL0) atomicAdd(&s_pc[cur][0], pcL0);
      if (ucL0) atomicAdd(&s_uc[cur][0], ucL0);
      if (pcL1) atomicAdd(&s_pc[cur][1], pcL1);
      if (ucL1) atomicAdd(&s_uc[cur][1], ucL1);
    }
    __syncthreads();   // B1

    int pcTA = s_pc[cur][0], ucA = s_uc[cur][0];
    int ndRaw = s_nd[cur];
    bool acceptA = (pcTA > 64) && (2 * (ucA - 1) > pcTA);  // ref uc excludes seed
    int labelA = count & 255;
    if (acceptA) count++;
    int removed = ucA;
    bool acceptB = false; int labelB = 0;
    if (dual) {
      int pcTB = s_pc[cur][1], ucB = s_uc[cur][1];
      acceptB = (pcTB > 64) && (2 * (ucB - 1) > pcTB);
      labelB = count & 255;
      if (acceptB) count++;
      removed += ucB;
    }
    ucount -= removed;
    if (tid == 0) { s_pc[nxt][0] = 0; s_pc[nxt][1] = 0;
                    s_uc[nxt][0] = 0; s_uc[nxt][1] = 0; s_nd[nxt] = 0; }

    // ---- labels (rare) — reuse unified queue ----
    if (acceptA || acceptB) {
      for (int c = wid; c < nc; c += 16) {
        int4 e = s_ck4[c];
        int cand = e.x >> 24;
        if (cand ? !acceptB : !acceptA) continue;
        int label = cand ? labelB : labelA;
        int i0 = e.x & 0xffffff;
        int hi = e.y, M0 = e.z, M1 = e.w;
        float CX = cand ? cxB : cxA;
        float CY = cand ? cyB : cyA;
        float D0 = cand ? den0B : den0A;
        float D1 = cand ? den1B : den1A;
        float I0 = cand ? inv0B : inv0A;
        float I1 = cand ? inv1B : inv1A;
        int i = i0 + lane, i2 = i + 64;
        if (i < hi && ((i >= M0 && i < M1) ||
                       prop_test(emb[i], CX, CY, D0, D1, I0, I1)))
          outb[pk[i].y] = label;
        if (i2 < hi && ((i2 >= M0 && i2 < M1) ||
                        prop_test(emb[i2], CX, CY, D0, D1, I0, I1)))
          outb[pk[i2].y] = label;
      }
    }

    // ---- rescans: only segments whose cached winner was removed ----
    if (ndRaw > DLCAP) {
      for (int s = wid; s < NSEG; s += 16)
        seg_rescan(s, V, lane, s_uncl, pk, emb, base, s_segkey, s_segkey2,
                   s_segci, s_segaux, true);
    } else {
      for (int d = wid; d < ndRaw; d += 16)
        seg_rescan(s_dlist[d], V, lane, s_uncl, pk, emb, base, s_segkey,
                   s_segkey2, s_segci, s_segaux, true);
    }
    __syncthreads();   // B2
    t++;
  }
}

// ---------------- launch ----------------

extern "C" void kernel_launch(void* const* d_in, const int* in_sizes, int n_in,
                              void* d_out, int out_size, void* d_ws, size_t ws_size,
                              hipStream_t stream) {
  const float* in = (const float*)d_in[0];
  int* out = (int*)d_out;

  size_t hist_bytes = (size_t)BATCH * NCELL * sizeof(int);
  size_t off_bytes  = (size_t)BATCH * (NCELL + 1) * sizeof(int);
  size_t cur_bytes  = (size_t)BATCH * NCELL * sizeof(int);
  size_t emb_bytes  = (size_t)BATCH * CCAP * sizeof(float2);
  size_t pk_bytes   = (size_t)BATCH * CCAP * sizeof(int2);

  size_t o_hist = 256;
  size_t o_off  = (o_hist + hist_bytes + 255) & ~(size_t)255;
  size_t o_cur  = (o_off + off_bytes + 255) & ~(size_t)255;
  size_t o_emb  = (o_cur + cur_bytes + 255) & ~(size_t)255;
  size_t o_pk   = (o_emb + emb_bytes + 255) & ~(size_t)255;
  size_t need   = o_pk + pk_bytes;

  if (ws_size < need) {
    fill_kernel<<<(out_size + 1023) / 1024, 1024, 0, stream>>>(out, 2000000, out_size);
    return;
  }

  int*    hist = (int*)((char*)d_ws + o_hist);
  int*    off  = (int*)((char*)d_ws + o_off);
  int*    cur  = (int*)((char*)d_ws + o_cur);
  float2* emb  = (float2*)((char*)d_ws + o_emb);
  int2*   pk   = (int2*)((char*)d_ws + o_pk);

  hipMemsetAsync(hist, 0, hist_bytes, stream);
  hist_kernel<<<(BATCH * NPIX) / 1024, 1024, 0, stream>>>(in, out, hist);
  scan_kernel<<<BATCH, 1024, 0, stream>>>(hist, off, cur);
  scatter_kernel<<<(BATCH * NPIX) / 1024, 1024, 0, stream>>>(in, cur, emb, pk);
  cluster_kernel<<<BATCH, 1024, 0, stream>>>(in, out, emb, pk, off);
}

// Round 11
// 973.577 us; speedup vs baseline: 1.0168x; 1.0168x over previous
//
#include <hip/hip_runtime.h>
#include <math.h>

#define BATCH 4
#define HH 512
#define WW 1024
#define NPIX (HH*WW)          // 524288 = 2^19
#define CCAP 196608           // compaction capacity per image (expected ~161.7k valid)
#define GX 64
#define GY 48
#define NCELL (GX*GY)         // 3072 cells, 0.0625 x 0.0625 over [-1,3]x[-1,2]
#define CELL 0.0625f
#define INVCELL 16.0f
#define SEGSZ 256             // pixels per argmax-cache segment
#define NSEGMAX (CCAP/SEGSZ)  // 768
#define DLCAP 1024            // dirty-segment list capacity
#define CKCAP 1024            // chunk queue capacity (worst observed ~300)

// ---------------- XLA:CPU f32 math replicas (unchanged from passing rounds) ----
__device__ __forceinline__ float xla_tanhf(float x) {
  if (fabsf(x) < 0.0004f) return x;
  float xc = fminf(fmaxf(x, -7.90531110763549805f), 7.90531110763549805f);
  float x2 = __fmul_rn(xc, xc);
  float p = -2.76076847742355e-16f;
  p = fmaf(x2, p, 2.00018790482477e-13f);
  p = fmaf(x2, p, -8.60467152213735e-11f);
  p = fmaf(x2, p, 5.12229709037114e-08f);
  p = fmaf(x2, p, 1.48572235717979e-05f);
  p = fmaf(x2, p, 6.37261928875436e-04f);
  p = fmaf(x2, p, 4.89352455891786e-03f);
  p = __fmul_rn(xc, p);
  float q = fmaf(x2, 1.19825839466702e-06f, 1.18534705686654e-04f);
  q = fmaf(x2, q, 2.26843463243900e-03f);
  q = fmaf(x2, q, 4.89352518554385e-03f);
  return __fdiv_rn(p, q);
}

__device__ __forceinline__ float xla_expf(float x) {
  float xc = fminf(fmaxf(x, -87.3365478515625f), 88.72283935546875f);
  float m = floorf(fmaf(xc, 1.44269504088896341f, 0.5f));
  float r = fmaf(m, -0.693359375f, xc);
  r = fmaf(m, 2.12194440e-4f, r);
  float r2 = __fmul_rn(r, r);
  float p = 1.9875691500e-4f;
  p = fmaf(p, r, 1.3981999507e-3f);
  p = fmaf(p, r, 8.3334519073e-3f);
  p = fmaf(p, r, 4.1665795894e-2f);
  p = fmaf(p, r, 1.6666665459e-1f);
  p = fmaf(p, r, 5.0000001201e-1f);
  float y = fmaf(r2, p, r);
  y = __fadd_rn(y, 1.0f);
  return ldexpf(y, (int)m);
}

__device__ __forceinline__ float xla_sigmoidf(float x) {
  return fmaf(0.5f, xla_tanhf(__fmul_rn(0.5f, x)), 0.5f);
}

// Proposal test — byte-identical decision logic to the passing kernels.
__device__ __forceinline__ bool prop_test(float2 e, float cx, float cy,
                                          float den0, float den1,
                                          float inv0, float inv1) {
  float d0 = __fsub_rn(e.x, cx), d1 = __fsub_rn(e.y, cy);
  float dd0 = __fmul_rn(d0, d0), dd1 = __fmul_rn(d1, d1);
  float zf = fmaf(dd0, inv0, __fmul_rn(dd1, inv1));
  if (zf < 0.6921472f) return true;
  if (zf <= 0.6941472f) {
    float t0 = __fdiv_rn(dd0, den0);
    float t1 = __fdiv_rn(dd1, den1);
    float z = __fadd_rn(t0, t1);
    return xla_expf(-z) > 0.5f;
  }
  return false;
}

__device__ __forceinline__ int cell_of_x(float ex) {
  int c = (int)((ex + 1.0f) * INVCELL);
  return min(max(c, 0), GX - 1);
}
__device__ __forceinline__ int cell_of_y(float ey) {
  int c = (int)((ey + 1.0f) * INVCELL);
  return min(max(c, 0), GY - 1);
}

// ---------------- kernels ----------------

__global__ __launch_bounds__(1024) void fill_kernel(int* out, int val, int n) {
  int i = blockIdx.x * 1024 + threadIdx.x;
  if (i < n) out[i] = val;
}

// pass A: zero output, LDS-aggregated histogram
__global__ __launch_bounds__(1024) void hist_kernel(const float* __restrict__ in,
                                                    int* __restrict__ out,
                                                    int* __restrict__ hist) {
  __shared__ int lh[NCELL];
  int tid = threadIdx.x;
  int gid = blockIdx.x * 1024 + tid;
  int b = gid >> 19;
  int p = gid & (NPIX - 1);
  for (int j = tid; j < NCELL; j += 1024) lh[j] = 0;
  __syncthreads();
  const float* base = in + (size_t)b * 5 * NPIX;
  float seed = base[(size_t)4 * NPIX + p];
  out[gid] = 0;
  if (seed > 0.5f) {
    float ox = base[p];
    float oy = base[(size_t)NPIX + p];
    int col = p & (WW - 1);
    int row = p >> 10;
    float gx = __fmul_rn((float)col, 2.0f / 1023.0f);
    float gy = __fmul_rn((float)row, 1.0f / 511.0f);
    float ex = __fadd_rn(xla_tanhf(ox), gx);
    float ey = __fadd_rn(xla_tanhf(oy), gy);
    atomicAdd(&lh[cell_of_y(ey) * GX + cell_of_x(ex)], 1);
  }
  __syncthreads();
  for (int j = tid; j < NCELL; j += 1024) {
    int c = lh[j];
    if (c) atomicAdd(&hist[b * NCELL + j], c);
  }
}

// pass B: exclusive scan of the cell counts per image
__global__ __launch_bounds__(1024) void scan_kernel(const int* __restrict__ hist,
                                                    int* __restrict__ off,
                                                    int* __restrict__ cursor) {
  __shared__ int s_c[NCELL];
  __shared__ int s_ps[1024];
  int b = blockIdx.x, t = threadIdx.x;
  const int* h = hist + b * NCELL;
  for (int i = t; i < NCELL; i += 1024) s_c[i] = h[i];
  __syncthreads();
  int a = s_c[3 * t], b2 = s_c[3 * t + 1], c2 = s_c[3 * t + 2];
  int th = a + b2 + c2;
  s_ps[t] = th;
  __syncthreads();
  for (int d = 1; d < 1024; d <<= 1) {
    int v = (t >= d) ? s_ps[t - d] : 0;
    __syncthreads();
    s_ps[t] += v;
    __syncthreads();
  }
  int excl = s_ps[t] - th;
  int* ob = off + b * (NCELL + 1);
  int* cb = cursor + b * NCELL;
  ob[3 * t] = excl;              cb[3 * t] = excl;
  ob[3 * t + 1] = excl + a;      cb[3 * t + 1] = excl + a;
  ob[3 * t + 2] = excl + a + b2; cb[3 * t + 2] = excl + a + b2;
  if (t == 1023) ob[NCELL] = s_ps[1023];
}

// pass C: LDS-aggregated scatter (within-cell order arbitrary; downstream is
// order-independent, tiebreak uses global pixel index)
__global__ __launch_bounds__(1024) void scatter_kernel(const float* __restrict__ in,
                                                       int* __restrict__ cursor,
                                                       float2* __restrict__ emb,
                                                       int2* __restrict__ pk) {
  __shared__ int lh[NCELL];
  __shared__ int lbase[NCELL];
  int tid = threadIdx.x;
  int gid = blockIdx.x * 1024 + tid;
  int b = gid >> 19;
  int p = gid & (NPIX - 1);
  for (int j = tid; j < NCELL; j += 1024) lh[j] = 0;
  __syncthreads();
  const float* base = in + (size_t)b * 5 * NPIX;
  float seed = base[(size_t)4 * NPIX + p];
  bool valid = seed > 0.5f;
  float ex = 0.0f, ey = 0.0f, smv = 0.0f;
  int cell = 0, sl = 0;
  if (valid) {
    float ox = base[p];
    float oy = base[(size_t)NPIX + p];
    int col = p & (WW - 1);
    int row = p >> 10;
    float gx = __fmul_rn((float)col, 2.0f / 1023.0f);
    float gy = __fmul_rn((float)row, 1.0f / 511.0f);
    ex = __fadd_rn(xla_tanhf(ox), gx);
    ey = __fadd_rn(xla_tanhf(oy), gy);
    smv = xla_sigmoidf(seed);
    cell = cell_of_y(ey) * GX + cell_of_x(ex);
    sl = atomicAdd(&lh[cell], 1);
  }
  __syncthreads();
  for (int j = tid; j < NCELL; j += 1024) {
    int c = lh[j];
    if (c) lbase[j] = atomicAdd(&cursor[b * NCELL + j], c);
  }
  __syncthreads();
  if (valid) {
    int slot = lbase[cell] + sl;
    if (slot < CCAP) {
      emb[(size_t)b * CCAP + slot] = make_float2(ex, ey);
      pk[(size_t)b * CCAP + slot]  = make_int2(__float_as_int(smv), p);
    }
  }
}

// Segment scan (single-key, from passing rounds 7-9).
__device__ __forceinline__ void seg_rescan(int s, int V, int lane,
    const unsigned* s_uncl, const int2* __restrict__ pk,
    const float2* __restrict__ emb, const float* __restrict__ base,
    unsigned long long* s_segkey, int* s_segci, float4* s_segaux,
    bool checkAlive) {
  unsigned long long bk = 0ULL; int bci = -1; int bpx = 0;
  #pragma unroll
  for (int j = 0; j < 4; ++j) {
    int i = (s << 8) + (j << 6) + lane;
    if (i < V) {
      bool alive = !checkAlive || ((s_uncl[i >> 5] >> (i & 31)) & 1u);
      if (alive) {
        int2 v = pk[i];
        unsigned long long k = ((unsigned long long)(unsigned)v.x << 32) | (unsigned)(~v.y);
        if (k > bk) { bk = k; bci = i; bpx = v.y; }
      }
    }
  }
  unsigned long long mk = bk; int mci = bci;
  #pragma unroll
  for (int o = 1; o < 64; o <<= 1) {
    unsigned long long ok = __shfl_xor(mk, o);
    int oci = __shfl_xor(mci, o);
    if (ok > mk) { mk = ok; mci = oci; }
  }
  if (lane == 0) { s_segkey[s] = mk; s_segci[s] = mci; }
  if (mk != 0ULL && bk == mk) {          // unique winner lane
    float2 e = emb[mci];
    float sxv = base[(size_t)2 * NPIX + bpx];
    float syv = base[(size_t)3 * NPIX + bpx];
    float d0 = __fmul_rn(2.0f, __fmul_rn(sxv, sxv));   // ref: 2.0 * s**2
    float d1 = __fmul_rn(2.0f, __fmul_rn(syv, syv));
    s_segaux[s] = make_float4(e.x, e.y, d0, d1);
  }
}

// Ballot-aggregated word clear for one 128-px chunk (proven r7-r9 logic).
__device__ __forceinline__ void clear_chunk(unsigned long long bm0,
    unsigned long long bm1, int i0, int lane, unsigned* s_uncl,
    const int* s_segci, int* s_dlist, int* s_nd_cur, int &pc, int &uc) {
  if ((bm0 | bm1) == 0ULL) return;
  int off = i0 & 31;
  unsigned w = (unsigned)(i0 >> 5);
  unsigned bits = 0; unsigned tw = w;
  if (lane == 0)      { pc += (int)__popcll(bm0); bits = (unsigned)(bm0 << off); tw = w; }
  else if (lane == 1) { bits = (unsigned)(bm0 >> (32 - off)); tw = w + 1; }
  else if (lane == 2) { if (off > 0) bits = (unsigned)(bm0 >> (64 - off)); tw = w + 2; }
  else if (lane == 3) { pc += (int)__popcll(bm1); bits = (unsigned)(bm1 << off); tw = w + 2; }
  else if (lane == 4) { bits = (unsigned)(bm1 >> (32 - off)); tw = w + 3; }
  else if (lane == 5) { if (off > 0) bits = (unsigned)(bm1 >> (64 - off)); tw = w + 4; }
  if (bits) {
    unsigned old = atomicAnd(&s_uncl[tw], ~bits);
    unsigned remv = old & bits;
    if (remv) {
      uc += __popc(remv);
      int seg = (int)(tw >> 3);           // 256 px = 8 words
      int ciw = s_segci[seg];
      if ((ciw >> 5) == (int)tw && ((remv >> (ciw & 31)) & 1u)) {
        int pos = atomicAdd(s_nd_cur, 1);
        if (pos < DLCAP) s_dlist[pos] = seg;
      }
    }
  }
}

// Chunk predicate eval (interior short-circuit; wave-uniform fast path).
__device__ __forceinline__ void chunk_pred(int4 e, int lane,
    const float2* __restrict__ emb, float cx, float cy,
    float den0, float den1, float inv0, float inv1,
    bool &p0, bool &p1) {
  int i0 = e.x, hi = e.y, M0 = e.z, M1 = e.w;
  int i = i0 + lane, i2 = i + 64;
  if (i0 >= M0 && i0 + 128 <= M1) { p0 = i < hi; p1 = i2 < hi; }
  else {
    p0 = (i < hi) && ((i >= M0 && i < M1) ||
                      prop_test(emb[i], cx, cy, den0, den1, inv0, inv1));
    p1 = (i2 < hi) && ((i2 >= M0 && i2 < M1) ||
                       prop_test(emb[i2], cx, cy, den0, den1, inv0, inv1));
  }
}

// One workgroup per image. 2 barriers/iteration. Self-contained int4 chunk
// queue, slice-written (pos%16==wid) so each wave reads only entries it wrote
// (wave-coherent, no barrier). Pass 1 processes 2 chunks per loop body so the
// 4 independent L2 emb loads overlap (software pipeline).
__global__ __launch_bounds__(1024) void cluster_kernel(const float* __restrict__ in,
                                                       int* __restrict__ out,
                                                       const float2* __restrict__ emb_all,
                                                       const int2* __restrict__ pk_all,
                                                       const int* __restrict__ off_g) {
  __shared__ unsigned int s_uncl[CCAP / 32];            // 24 KB
  __shared__ int s_off[NCELL + 1];                      // 12 KB
  __shared__ unsigned long long s_segkey[NSEGMAX];      // 6 KB
  __shared__ int s_segci[NSEGMAX];                      // 3 KB
  __shared__ float4 s_segaux[NSEGMAX];                  // 12 KB
  __shared__ int s_dlist[DLCAP];                        // 4 KB
  __shared__ int4 s_ck4[CKCAP];                         // 16 KB
  __shared__ int s_pc[2];
  __shared__ int s_uc[2];
  __shared__ int s_nd[2];

  int b = blockIdx.x;
  int tid = threadIdx.x;
  int lane = tid & 63;
  int wid = tid >> 6;
  const int* offb = off_g + b * (NCELL + 1);
  int V = offb[NCELL];
  const float2* emb = emb_all + (size_t)b * CCAP;
  const int2*   pk  = pk_all  + (size_t)b * CCAP;
  int* outb = out + (size_t)b * NPIX;
  const float* base = in + (size_t)b * 5 * NPIX;

  if (V > CCAP) {   // capacity overflow marker
    for (int i = tid; i < NPIX; i += 1024) outb[i] = 1000000;
    return;
  }
  int NSEG = (V + SEGSZ - 1) >> 8;

  for (int i = tid; i <= NCELL; i += 1024) s_off[i] = offb[i];
  for (int w = tid; w < CCAP / 32; w += 1024) {
    int basebit = w << 5;
    unsigned m;
    if (basebit + 32 <= V)      m = 0xffffffffu;
    else if (basebit >= V)      m = 0u;
    else                        m = (1u << (V - basebit)) - 1u;
    s_uncl[w] = m;
  }
  if (tid < 2) { s_pc[tid] = 0; s_uc[tid] = 0; s_nd[tid] = 0; }
  __syncthreads();

  for (int s = wid; s < NSEG; s += 16)
    seg_rescan(s, V, lane, s_uncl, pk, emb, base, s_segkey, s_segci, s_segaux, false);
  __syncthreads();

  int ucount = V, count = 1, guard = 0;
  int t = 0;
  while (ucount > 64 && guard++ <= CCAP) {
    int cur = t & 1, nxt = cur ^ 1;

    // ---- wave-redundant argmax: key-only shfl reduce + ballot recovery ----
    unsigned long long lk = 0ULL; int lsg = -1;
    for (int s = lane; s < NSEG; s += 64) {
      unsigned long long v = s_segkey[s];
      if (v > lk) { lk = v; lsg = s; }
    }
    unsigned long long gk = lk;
    #pragma unroll
    for (int o = 1; o < 64; o <<= 1) {
      unsigned long long ok = __shfl_xor(gk, o);
      if (ok > gk) gk = ok;
    }
    if (gk == 0ULL) break;
    float sm = __uint_as_float((unsigned)(gk >> 32));
    if (sm < 0.5f) break;              // ref's new_done (provably never fires)
    unsigned long long bmask = __ballot(lk == gk);   // keys unique -> one lane
    int src = __builtin_ctzll(bmask);
    int sg = __shfl(lsg, src);

    float4 aux = s_segaux[sg];         // broadcast LDS read
    float cx = aux.x, cy = aux.y, den0 = aux.z, den1 = aux.w;
    float inv0 = 1.0f / den0;
    float inv1 = 1.0f / den1;
    float ry = sqrtf(__fmul_rn(den1, 0.6971472f)) * 1.00001f;
    int r0 = cell_of_y(cy - ry);
    int r1 = cell_of_y(cy + ry);
    int nr = r1 - r0 + 1;              // <= 19

    // ---- per-lane row geometry + slice-written int4 chunk queue ----
    int ck = 0, rs_l = 0, re_l = 0, m0_l = 0, m1_l = 0;
    if (lane < nr) {
      int r = r0 + lane;
      float ylo = fmaf((float)r, CELL, -1.0f);
      float dy = fmaxf(0.0f, fmaxf(ylo - cy, cy - (ylo + CELL))) * 0.999999f;
      float rem = 0.6971472f - dy * dy * inv1;
      if (rem > 0.0f) {
        float dxm = sqrtf(den0 * rem) * 1.00001f;
        int c0 = cell_of_x(cx - dxm), c1 = cell_of_x(cx + dxm);
        int rbase = r * GX;
        rs_l = s_off[rbase + c0]; re_l = s_off[rbase + c1 + 1];
        m0_l = rs_l; m1_l = rs_l;
        float dyc = fmaxf(fabsf(ylo - cy), fabsf(ylo + CELL - cy)) + 1e-5f;
        float remI = 0.6920f - dyc * dyc * inv1;
        if (remI > 0.0f) {
          float dxin = sqrtf(den0 * remI) * 0.9999f;
          int a  = (int)ceilf(fmaf(cx - dxin, INVCELL, INVCELL) + 1e-3f);
          int bb = (int)floorf(fmaf(cx + dxin, INVCELL, INVCELL) - 1e-3f) - 1;
          a = max(a, c0); bb = min(bb, c1);
          if (a <= bb) { m0_l = s_off[rbase + a]; m1_l = s_off[rbase + bb + 1]; }
        }
        ck = (re_l - rs_l + 127) >> 7;
      }
    }
    int cum = ck;                       // 5-step prefix over lanes 0..31 (nr<=19)
    #pragma unroll
    for (int o = 1; o < 32; o <<= 1) {
      int u = __shfl_up(cum, o);
      if (lane >= o) cum += u;
    }
    int nc = __shfl(cum, 31);
    int excl = cum - ck;
    for (int k = 0; k < ck; ++k) {
      int pos = excl + k;
      if ((pos & 15) == wid && pos < CKCAP) {
        int i0 = rs_l + (k << 7);
        s_ck4[pos] = make_int4(i0, min(i0 + 128, re_l), m0_l, m1_l);
      }
    }
    if (nc > CKCAP) nc = CKCAP;   // fixed-input observed max ~300; safety clamp

    // ---- pass 1: 2 chunks per body — 4 independent L2 loads in flight ----
    int pc = 0, uc = 0;
    for (int c = wid; c < nc; c += 32) {
      int4 e1 = s_ck4[c];
      int c2i = c + 16;
      bool has2 = c2i < nc;
      bool q0, q1, r0v = false, r1v = false;
      int4 e2 = has2 ? s_ck4[c2i] : make_int4(0, 0, 0, 0);
      chunk_pred(e1, lane, emb, cx, cy, den0, den1, inv0, inv1, q0, q1);
      if (has2)
        chunk_pred(e2, lane, emb, cx, cy, den0, den1, inv0, inv1, r0v, r1v);
      unsigned long long bm0 = __ballot(q0);
      unsigned long long bm1 = __ballot(q1);
      clear_chunk(bm0, bm1, e1.x, lane, s_uncl, s_segci, s_dlist, &s_nd[cur], pc, uc);
      if (has2) {
        unsigned long long bm2 = __ballot(r0v);
        unsigned long long bm3 = __ballot(r1v);
        clear_chunk(bm2, bm3, e2.x, lane, s_uncl, s_segci, s_dlist, &s_nd[cur], pc, uc);
      }
    }
    #pragma unroll
    for (int o = 32; o > 0; o >>= 1) {
      pc += __shfl_down(pc, o);
      uc += __shfl_down(uc, o);
    }
    if (lane == 0 && (pc | uc)) {
      if (pc) atomicAdd(&s_pc[cur], pc);
      if (uc) atomicAdd(&s_uc[cur], uc);
    }
    __syncthreads();   // B1

    int pcT = s_pc[cur];
    int ucR = s_uc[cur];            // total removed this iter (includes seed)
    int ndRaw = s_nd[cur];
    bool accept = (pcT > 64) && (2 * (ucR - 1) > pcT);  // ref uc excludes seed
    int label = count & 255;
    if (accept) count++;
    ucount -= ucR;
    if (tid == 0) { s_pc[nxt] = 0; s_uc[nxt] = 0; s_nd[nxt] = 0; }

    // ---- labels (rare: only accepted iterations) — reuse own queue slice ----
    if (accept) {
      for (int c = wid; c < nc; c += 16) {
        int4 e = s_ck4[c];
        int i0 = e.x, hi = e.y, M0 = e.z, M1 = e.w;
        int i = i0 + lane, i2 = i + 64;
        if (i < hi && ((i >= M0 && i < M1) ||
                       prop_test(emb[i], cx, cy, den0, den1, inv0, inv1)))
          outb[pk[i].y] = label;
        if (i2 < hi && ((i2 >= M0 && i2 < M1) ||
                        prop_test(emb[i2], cx, cy, den0, den1, inv0, inv1)))
          outb[pk[i2].y] = label;
      }
    }

    // ---- rescans: only segments whose cached winner was removed ----
    if (ndRaw > DLCAP) {
      for (int s = wid; s < NSEG; s += 16)
        seg_rescan(s, V, lane, s_uncl, pk, emb, base, s_segkey, s_segci, s_segaux, true);
    } else {
      for (int d = wid; d < ndRaw; d += 16)
        seg_rescan(s_dlist[d], V, lane, s_uncl, pk, emb, base, s_segkey,
                   s_segci, s_segaux, true);
    }
    __syncthreads();   // B2
    t++;
  }
}

// ---------------- launch ----------------

extern "C" void kernel_launch(void* const* d_in, const int* in_sizes, int n_in,
                              void* d_out, int out_size, void* d_ws, size_t ws_size,
                              hipStream_t stream) {
  const float* in = (const float*)d_in[0];
  int* out = (int*)d_out;

  size_t hist_bytes = (size_t)BATCH * NCELL * sizeof(int);
  size_t off_bytes  = (size_t)BATCH * (NCELL + 1) * sizeof(int);
  size_t cur_bytes  = (size_t)BATCH * NCELL * sizeof(int);
  size_t emb_bytes  = (size_t)BATCH * CCAP * sizeof(float2);
  size_t pk_bytes   = (size_t)BATCH * CCAP * sizeof(int2);

  size_t o_hist = 256;
  size_t o_off  = (o_hist + hist_bytes + 255) & ~(size_t)255;
  size_t o_cur  = (o_off + off_bytes + 255) & ~(size_t)255;
  size_t o_emb  = (o_cur + cur_bytes + 255) & ~(size_t)255;
  size_t o_pk   = (o_emb + emb_bytes + 255) & ~(size_t)255;
  size_t need   = o_pk + pk_bytes;

  if (ws_size < need) {
    fill_kernel<<<(out_size + 1023) / 1024, 1024, 0, stream>>>(out, 2000000, out_size);
    return;
  }

  int*    hist = (int*)((char*)d_ws + o_hist);
  int*    off  = (int*)((char*)d_ws + o_off);
  int*    cur  = (int*)((char*)d_ws + o_cur);
  float2* emb  = (float2*)((char*)d_ws + o_emb);
  int2*   pk   = (int2*)((char*)d_ws + o_pk);

  hipMemsetAsync(hist, 0, hist_bytes, stream);
  hist_kernel<<<(BATCH * NPIX) / 1024, 1024, 0, stream>>>(in, out, hist);
  scan_kernel<<<BATCH, 1024, 0, stream>>>(hist, off, cur);
  scatter_kernel<<<(BATCH * NPIX) / 1024, 1024, 0, stream>>>(in, cur, emb, pk);
  cluster_kernel<<<BATCH, 1024, 0, stream>>>(in, out, emb, pk, off);
}

// Round 12
// 937.472 us; speedup vs baseline: 1.0559x; 1.0385x over previous
//
#include <hip/hip_runtime.h>
#include <math.h>

#define BATCH 4
#define HH 512
#define WW 1024
#define NPIX (HH*WW)          // 524288 = 2^19
#define CCAP 196608           // compaction capacity per image (expected ~161.7k valid)
#define GX 64
#define GY 48
#define NCELL (GX*GY)         // 3072 cells, 0.0625 x 0.0625 over [-1,3]x[-1,2]
#define CELL 0.0625f
#define INVCELL 16.0f
#define SEGSZ 256             // pixels per argmax-cache segment
#define NSEGMAX (CCAP/SEGSZ)  // 768
#define DLCAP 2048            // dirty-segment list capacity
#define CKCAP 1600            // chunk queue capacity (worst observed ~300)

// ---------------- XLA:CPU f32 math replicas (unchanged from passing rounds) ----
__device__ __forceinline__ float xla_tanhf(float x) {
  if (fabsf(x) < 0.0004f) return x;
  float xc = fminf(fmaxf(x, -7.90531110763549805f), 7.90531110763549805f);
  float x2 = __fmul_rn(xc, xc);
  float p = -2.76076847742355e-16f;
  p = fmaf(x2, p, 2.00018790482477e-13f);
  p = fmaf(x2, p, -8.60467152213735e-11f);
  p = fmaf(x2, p, 5.12229709037114e-08f);
  p = fmaf(x2, p, 1.48572235717979e-05f);
  p = fmaf(x2, p, 6.37261928875436e-04f);
  p = fmaf(x2, p, 4.89352455891786e-03f);
  p = __fmul_rn(xc, p);
  float q = fmaf(x2, 1.19825839466702e-06f, 1.18534705686654e-04f);
  q = fmaf(x2, q, 2.26843463243900e-03f);
  q = fmaf(x2, q, 4.89352518554385e-03f);
  return __fdiv_rn(p, q);
}

__device__ __forceinline__ float xla_expf(float x) {
  float xc = fminf(fmaxf(x, -87.3365478515625f), 88.72283935546875f);
  float m = floorf(fmaf(xc, 1.44269504088896341f, 0.5f));
  float r = fmaf(m, -0.693359375f, xc);
  r = fmaf(m, 2.12194440e-4f, r);
  float r2 = __fmul_rn(r, r);
  float p = 1.9875691500e-4f;
  p = fmaf(p, r, 1.3981999507e-3f);
  p = fmaf(p, r, 8.3334519073e-3f);
  p = fmaf(p, r, 4.1665795894e-2f);
  p = fmaf(p, r, 1.6666665459e-1f);
  p = fmaf(p, r, 5.0000001201e-1f);
  float y = fmaf(r2, p, r);
  y = __fadd_rn(y, 1.0f);
  return ldexpf(y, (int)m);
}

__device__ __forceinline__ float xla_sigmoidf(float x) {
  return fmaf(0.5f, xla_tanhf(__fmul_rn(0.5f, x)), 0.5f);
}

// Proposal test — byte-identical decision logic to the passing kernels.
__device__ __forceinline__ bool prop_test(float2 e, float cx, float cy,
                                          float den0, float den1,
                                          float inv0, float inv1) {
  float d0 = __fsub_rn(e.x, cx), d1 = __fsub_rn(e.y, cy);
  float dd0 = __fmul_rn(d0, d0), dd1 = __fmul_rn(d1, d1);
  float zf = fmaf(dd0, inv0, __fmul_rn(dd1, inv1));
  if (zf < 0.6921472f) return true;
  if (zf <= 0.6941472f) {
    float t0 = __fdiv_rn(dd0, den0);
    float t1 = __fdiv_rn(dd1, den1);
    float z = __fadd_rn(t0, t1);
    return xla_expf(-z) > 0.5f;
  }
  return false;
}

__device__ __forceinline__ int cell_of_x(float ex) {
  int c = (int)((ex + 1.0f) * INVCELL);
  return min(max(c, 0), GX - 1);
}
__device__ __forceinline__ int cell_of_y(float ey) {
  int c = (int)((ey + 1.0f) * INVCELL);
  return min(max(c, 0), GY - 1);
}

// ---------------- kernels ----------------

__global__ __launch_bounds__(1024) void fill_kernel(int* out, int val, int n) {
  int i = blockIdx.x * 1024 + threadIdx.x;
  if (i < n) out[i] = val;
}

// pass A: zero output, LDS-aggregated histogram (one global atomic per block+cell)
__global__ __launch_bounds__(1024) void hist_kernel(const float* __restrict__ in,
                                                    int* __restrict__ out,
                                                    int* __restrict__ hist) {
  __shared__ int lh[NCELL];
  int tid = threadIdx.x;
  int gid = blockIdx.x * 1024 + tid;
  int b = gid >> 19;
  int p = gid & (NPIX - 1);
  for (int j = tid; j < NCELL; j += 1024) lh[j] = 0;
  __syncthreads();
  const float* base = in + (size_t)b * 5 * NPIX;
  float seed = base[(size_t)4 * NPIX + p];
  out[gid] = 0;
  if (seed > 0.5f) {
    float ox = base[p];
    float oy = base[(size_t)NPIX + p];
    int col = p & (WW - 1);
    int row = p >> 10;
    float gx = __fmul_rn((float)col, 2.0f / 1023.0f);
    float gy = __fmul_rn((float)row, 1.0f / 511.0f);
    float ex = __fadd_rn(xla_tanhf(ox), gx);
    float ey = __fadd_rn(xla_tanhf(oy), gy);
    atomicAdd(&lh[cell_of_y(ey) * GX + cell_of_x(ex)], 1);
  }
  __syncthreads();
  for (int j = tid; j < NCELL; j += 1024) {
    int c = lh[j];
    if (c) atomicAdd(&hist[b * NCELL + j], c);
  }
}

// pass B: exclusive scan of the cell counts per image (one block per image)
__global__ __launch_bounds__(1024) void scan_kernel(const int* __restrict__ hist,
                                                    int* __restrict__ off,
                                                    int* __restrict__ cursor) {
  __shared__ int s_c[NCELL];
  __shared__ int s_ps[1024];
  int b = blockIdx.x, t = threadIdx.x;
  const int* h = hist + b * NCELL;
  for (int i = t; i < NCELL; i += 1024) s_c[i] = h[i];
  __syncthreads();
  int a = s_c[3 * t], b2 = s_c[3 * t + 1], c2 = s_c[3 * t + 2];
  int th = a + b2 + c2;
  s_ps[t] = th;
  __syncthreads();
  for (int d = 1; d < 1024; d <<= 1) {
    int v = (t >= d) ? s_ps[t - d] : 0;
    __syncthreads();
    s_ps[t] += v;
    __syncthreads();
  }
  int excl = s_ps[t] - th;
  int* ob = off + b * (NCELL + 1);
  int* cb = cursor + b * NCELL;
  ob[3 * t] = excl;              cb[3 * t] = excl;
  ob[3 * t + 1] = excl + a;      cb[3 * t + 1] = excl + a;
  ob[3 * t + 2] = excl + a + b2; cb[3 * t + 2] = excl + a + b2;
  if (t == 1023) ob[NCELL] = s_ps[1023];
}

// pass C: LDS-aggregated scatter (within-cell order arbitrary; downstream is
// order-independent, tiebreak uses global pixel index)
__global__ __launch_bounds__(1024) void scatter_kernel(const float* __restrict__ in,
                                                       int* __restrict__ cursor,
                                                       float2* __restrict__ emb,
                                                       int2* __restrict__ pk) {
  __shared__ int lh[NCELL];
  __shared__ int lbase[NCELL];
  int tid = threadIdx.x;
  int gid = blockIdx.x * 1024 + tid;
  int b = gid >> 19;
  int p = gid & (NPIX - 1);
  for (int j = tid; j < NCELL; j += 1024) lh[j] = 0;
  __syncthreads();
  const float* base = in + (size_t)b * 5 * NPIX;
  float seed = base[(size_t)4 * NPIX + p];
  bool valid = seed > 0.5f;
  float ex = 0.0f, ey = 0.0f, smv = 0.0f;
  int cell = 0, sl = 0;
  if (valid) {
    float ox = base[p];
    float oy = base[(size_t)NPIX + p];
    int col = p & (WW - 1);
    int row = p >> 10;
    float gx = __fmul_rn((float)col, 2.0f / 1023.0f);
    float gy = __fmul_rn((float)row, 1.0f / 511.0f);
    ex = __fadd_rn(xla_tanhf(ox), gx);
    ey = __fadd_rn(xla_tanhf(oy), gy);
    smv = xla_sigmoidf(seed);
    cell = cell_of_y(ey) * GX + cell_of_x(ex);
    sl = atomicAdd(&lh[cell], 1);
  }
  __syncthreads();
  for (int j = tid; j < NCELL; j += 1024) {
    int c = lh[j];
    if (c) lbase[j] = atomicAdd(&cursor[b * NCELL + j], c);
  }
  __syncthreads();
  if (valid) {
    int slot = lbase[cell] + sl;
    if (slot < CCAP) {
      emb[(size_t)b * CCAP + slot] = make_float2(ex, ey);
      pk[(size_t)b * CCAP + slot]  = make_int2(__float_as_int(smv), p);
    }
  }
}

// Segment scan helper (unchanged from passing rounds 7/8).
__device__ __forceinline__ void seg_rescan(int s, int V, int lane,
    const unsigned* s_uncl, const int2* __restrict__ pk,
    const float2* __restrict__ emb, const float* __restrict__ base,
    unsigned long long* s_segkey, int* s_segci, float4* s_segaux,
    bool checkAlive) {
  unsigned long long bk = 0ULL; int bci = -1; int bpx = 0;
  #pragma unroll
  for (int j = 0; j < 4; ++j) {
    int i = (s << 8) + (j << 6) + lane;
    if (i < V) {
      bool alive = !checkAlive || ((s_uncl[i >> 5] >> (i & 31)) & 1u);
      if (alive) {
        int2 v = pk[i];
        unsigned long long k = ((unsigned long long)(unsigned)v.x << 32) | (unsigned)(~v.y);
        if (k > bk) { bk = k; bci = i; bpx = v.y; }
      }
    }
  }
  unsigned long long mk = bk; int mci = bci;
  #pragma unroll
  for (int o = 1; o < 64; o <<= 1) {
    unsigned long long ok = __shfl_xor(mk, o);
    int oci = __shfl_xor(mci, o);
    if (ok > mk) { mk = ok; mci = oci; }
  }
  if (lane == 0) { s_segkey[s] = mk; s_segci[s] = mci; }
  if (mk != 0ULL && bk == mk) {          // unique winner lane
    float2 e = emb[mci];
    float sxv = base[(size_t)2 * NPIX + bpx];
    float syv = base[(size_t)3 * NPIX + bpx];
    float d0 = __fmul_rn(2.0f, __fmul_rn(sxv, sxv));   // ref: 2.0 * s**2
    float d1 = __fmul_rn(2.0f, __fmul_rn(syv, syv));
    s_segaux[s] = make_float4(e.x, e.y, d0, d1);
  }
}

// One workgroup per image. 2 barriers/iteration. Pass-1 work is a flat 128-px
// chunk queue (built redundantly per wave; benign identical-value LDS races)
// consumed round-robin by all 16 waves — removes wave-pair load imbalance.
__global__ __launch_bounds__(1024) void cluster_kernel(const float* __restrict__ in,
                                                       int* __restrict__ out,
                                                       const float2* __restrict__ emb_all,
                                                       const int2* __restrict__ pk_all,
                                                       const int* __restrict__ off_g) {
  __shared__ unsigned int s_uncl[CCAP / 32];            // 24 KB
  __shared__ int s_off[NCELL + 1];                      // 12 KB
  __shared__ unsigned long long s_segkey[NSEGMAX];      // 6 KB
  __shared__ int s_segci[NSEGMAX];                      // 3 KB
  __shared__ float4 s_segaux[NSEGMAX];                  // 12 KB
  __shared__ int s_dlist[DLCAP];                        // 8 KB
  __shared__ int s_ck[CKCAP];                           // 6.4 KB
  __shared__ int4 s_row4[24];                           // 384 B
  __shared__ int s_pc[2];
  __shared__ int s_uc[2];
  __shared__ int s_nd[2];

  int b = blockIdx.x;
  int tid = threadIdx.x;
  int lane = tid & 63;
  int wid = tid >> 6;
  const int* offb = off_g + b * (NCELL + 1);
  int V = offb[NCELL];
  const float2* emb = emb_all + (size_t)b * CCAP;
  const int2*   pk  = pk_all  + (size_t)b * CCAP;
  int* outb = out + (size_t)b * NPIX;
  const float* base = in + (size_t)b * 5 * NPIX;

  if (V > CCAP) {   // capacity overflow marker
    for (int i = tid; i < NPIX; i += 1024) outb[i] = 1000000;
    return;
  }
  int NSEG = (V + SEGSZ - 1) >> 8;

  for (int i = tid; i <= NCELL; i += 1024) s_off[i] = offb[i];
  for (int w = tid; w < CCAP / 32; w += 1024) {
    int basebit = w << 5;
    unsigned m;
    if (basebit + 32 <= V)      m = 0xffffffffu;
    else if (basebit >= V)      m = 0u;
    else                        m = (1u << (V - basebit)) - 1u;
    s_uncl[w] = m;
  }
  if (tid < 2) { s_pc[tid] = 0; s_uc[tid] = 0; s_nd[tid] = 0; }
  __syncthreads();

  // build segment caches (all pixels alive)
  for (int s = wid; s < NSEG; s += 16)
    seg_rescan(s, V, lane, s_uncl, pk, emb, base, s_segkey, s_segci, s_segaux, false);
  __syncthreads();

  int ucount = V, count = 1, guard = 0;
  int t = 0;
  while (ucount > 64 && guard++ <= CCAP) {
    int cur = t & 1, nxt = cur ^ 1;

    // ---- wave-redundant argmax: key-only shfl reduce + ballot recovery ----
    unsigned long long lk = 0ULL; int lsg = -1;
    for (int s = lane; s < NSEG; s += 64) {
      unsigned long long v = s_segkey[s];
      if (v > lk) { lk = v; lsg = s; }
    }
    unsigned long long gk = lk;
    #pragma unroll
    for (int o = 1; o < 64; o <<= 1) {
      unsigned long long ok = __shfl_xor(gk, o);
      if (ok > gk) gk = ok;
    }
    if (gk == 0ULL) break;
    float sm = __uint_as_float((unsigned)(gk >> 32));
    if (sm < 0.5f) break;              // ref's new_done (provably never fires)
    unsigned long long bmask = __ballot(lk == gk);   // keys unique -> one lane
    int src = __builtin_ctzll(bmask);
    int sg = __shfl(lsg, src);

    float4 aux = s_segaux[sg];         // broadcast LDS read
    float cx = aux.x, cy = aux.y, den0 = aux.z, den1 = aux.w;
    float inv0 = 1.0f / den0;
    float inv1 = 1.0f / den1;
    float ry = sqrtf(__fmul_rn(den1, 0.6971472f)) * 1.00001f;
    int r0 = cell_of_y(cy - ry);
    int r1 = cell_of_y(cy + ry);
    int nr = r1 - r0 + 1;              // <= 19

    // ---- per-lane row geometry + chunk queue build (redundant per wave) ----
    int ck = 0, rs_l = 0, re_l = 0, m0_l = 0, m1_l = 0;
    if (lane < nr) {
      int r = r0 + lane;
      float ylo = fmaf((float)r, CELL, -1.0f);
      float dy = fmaxf(0.0f, fmaxf(ylo - cy, cy - (ylo + CELL))) * 0.999999f;
      float rem = 0.6971472f - dy * dy * inv1;
      if (rem > 0.0f) {
        float dxm = sqrtf(den0 * rem) * 1.00001f;
        int c0 = cell_of_x(cx - dxm), c1 = cell_of_x(cx + dxm);
        int rbase = r * GX;
        rs_l = s_off[rbase + c0]; re_l = s_off[rbase + c1 + 1];
        m0_l = rs_l; m1_l = rs_l;
        float dyc = fmaxf(fabsf(ylo - cy), fabsf(ylo + CELL - cy)) + 1e-5f;
        float remI = 0.6920f - dyc * dyc * inv1;
        if (remI > 0.0f) {
          float dxin = sqrtf(den0 * remI) * 0.9999f;
          int a  = (int)ceilf(fmaf(cx - dxin, INVCELL, INVCELL) + 1e-3f);
          int bb = (int)floorf(fmaf(cx + dxin, INVCELL, INVCELL) - 1e-3f) - 1;
          a = max(a, c0); bb = min(bb, c1);
          if (a <= bb) { m0_l = s_off[rbase + a]; m1_l = s_off[rbase + bb + 1]; }
        }
        ck = (re_l - rs_l + 127) >> 7;
      }
    }
    int cum = ck;                       // 5-step prefix over lanes 0..31 (nr<=19)
    #pragma unroll
    for (int o = 1; o < 32; o <<= 1) {
      int u = __shfl_up(cum, o);
      if (lane >= o) cum += u;
    }
    int nc = __shfl(cum, 31);
    int excl = cum - ck;
    if (lane < nr && ck) {
      s_row4[lane] = make_int4(m0_l, m1_l, re_l, 0);
      for (int k = 0; k < ck; ++k)
        s_ck[excl + k] = (lane << 24) | (rs_l + (k << 7));
    }

    // ---- pass 1: chunk queue, all waves round-robin ----
    int pc = 0, uc = 0;
    for (int c = wid; c < nc; c += 16) {
      int e = s_ck[c];
      int rl = e >> 24;
      int i0 = e & 0xffffff;
      int4 rw = s_row4[rl];             // m0, m1, re
      int hi = min(i0 + 128, rw.z);
      int i = i0 + lane, i2 = i + 64;
      bool p0, p1;
      if (i0 >= rw.x && i0 + 128 <= rw.y) {   // fully-interior chunk: no loads
        p0 = i < hi; p1 = i2 < hi;
      } else {
        p0 = (i < hi) && ((i >= rw.x && i < rw.y) ||
                          prop_test(emb[i], cx, cy, den0, den1, inv0, inv1));
        p1 = (i2 < hi) && ((i2 >= rw.x && i2 < rw.y) ||
                           prop_test(emb[i2], cx, cy, den0, den1, inv0, inv1));
      }
      unsigned long long bm0 = __ballot(p0);
      unsigned long long bm1 = __ballot(p1);
      if ((bm0 | bm1) == 0ULL) continue;
      int off = i0 & 31;
      unsigned w = (unsigned)(i0 >> 5);
      unsigned bits = 0; unsigned tw = w;
      if (lane == 0)      { pc += (int)__popcll(bm0); bits = (unsigned)(bm0 << off); tw = w; }
      else if (lane == 1) { bits = (unsigned)(bm0 >> (32 - off)); tw = w + 1; }
      else if (lane == 2) { if (off > 0) bits = (unsigned)(bm0 >> (64 - off)); tw = w + 2; }
      else if (lane == 3) { pc += (int)__popcll(bm1); bits = (unsigned)(bm1 << off); tw = w + 2; }
      else if (lane == 4) { bits = (unsigned)(bm1 >> (32 - off)); tw = w + 3; }
      else if (lane == 5) { if (off > 0) bits = (unsigned)(bm1 >> (64 - off)); tw = w + 4; }
      if (bits) {
        unsigned old = atomicAnd(&s_uncl[tw], ~bits);
        unsigned remv = old & bits;
        if (remv) {
          uc += __popc(remv);
          int seg = (int)(tw >> 3);           // 256 px = 8 words
          int ciw = s_segci[seg];
          if ((ciw >> 5) == (int)tw && ((remv >> (ciw & 31)) & 1u)) {
            int pos = atomicAdd(&s_nd[cur], 1);
            if (pos < DLCAP) s_dlist[pos] = seg;
          }
        }
      }
    }
    for (int o = 32; o > 0; o >>= 1) {
      pc += __shfl_down(pc, o);
      uc += __shfl_down(uc, o);
    }
    if (lane == 0 && (pc | uc)) {
      if (pc) atomicAdd(&s_pc[cur], pc);
      if (uc) atomicAdd(&s_uc[cur], uc);
    }
    __syncthreads();   // B1

    int pcT = s_pc[cur];
    int ucR = s_uc[cur];            // total removed this iter (includes seed)
    int ndRaw = s_nd[cur];
    bool accept = (pcT > 64) && (2 * (ucR - 1) > pcT);  // ref uc excludes seed
    int label = count & 255;
    if (accept) count++;
    ucount -= ucR;
    if (tid == 0) { s_pc[nxt] = 0; s_uc[nxt] = 0; s_nd[nxt] = 0; }

    // ---- labels (rare: only accepted iterations) — reuse chunk queue ----
    if (accept) {
      for (int c = wid; c < nc; c += 16) {
        int e = s_ck[c];
        int rl = e >> 24;
        int i0 = e & 0xffffff;
        int4 rw = s_row4[rl];
        int hi = min(i0 + 128, rw.z);
        int i = i0 + lane, i2 = i + 64;
        if (i < hi && ((i >= rw.x && i < rw.y) ||
                       prop_test(emb[i], cx, cy, den0, den1, inv0, inv1)))
          outb[pk[i].y] = label;
        if (i2 < hi && ((i2 >= rw.x && i2 < rw.y) ||
                        prop_test(emb[i2], cx, cy, den0, den1, inv0, inv1)))
          outb[pk[i2].y] = label;
      }
    }

    // ---- rescans: only segments whose cached winner was removed ----
    if (ndRaw > DLCAP) {
      for (int s = wid; s < NSEG; s += 16)
        seg_rescan(s, V, lane, s_uncl, pk, emb, base, s_segkey, s_segci, s_segaux, true);
    } else {
      for (int d = wid; d < ndRaw; d += 16)
        seg_rescan(s_dlist[d], V, lane, s_uncl, pk, emb, base, s_segkey,
                   s_segci, s_segaux, true);
    }
    __syncthreads();   // B2
    t++;
  }
}

// ---------------- launch ----------------

extern "C" void kernel_launch(void* const* d_in, const int* in_sizes, int n_in,
                              void* d_out, int out_size, void* d_ws, size_t ws_size,
                              hipStream_t stream) {
  const float* in = (const float*)d_in[0];
  int* out = (int*)d_out;

  size_t hist_bytes = (size_t)BATCH * NCELL * sizeof(int);
  size_t off_bytes  = (size_t)BATCH * (NCELL + 1) * sizeof(int);
  size_t cur_bytes  = (size_t)BATCH * NCELL * sizeof(int);
  size_t emb_bytes  = (size_t)BATCH * CCAP * sizeof(float2);
  size_t pk_bytes   = (size_t)BATCH * CCAP * sizeof(int2);

  size_t o_hist = 256;
  size_t o_off  = (o_hist + hist_bytes + 255) & ~(size_t)255;
  size_t o_cur  = (o_off + off_bytes + 255) & ~(size_t)255;
  size_t o_emb  = (o_cur + cur_bytes + 255) & ~(size_t)255;
  size_t o_pk   = (o_emb + emb_bytes + 255) & ~(size_t)255;
  size_t need   = o_pk + pk_bytes;

  if (ws_size < need) {
    fill_kernel<<<(out_size + 1023) / 1024, 1024, 0, stream>>>(out, 2000000, out_size);
    return;
  }

  int*    hist = (int*)((char*)d_ws + o_hist);
  int*    off  = (int*)((char*)d_ws + o_off);
  int*    cur  = (int*)((char*)d_ws + o_cur);
  float2* emb  = (float2*)((char*)d_ws + o_emb);
  int2*   pk   = (int2*)((char*)d_ws + o_pk);

  hipMemsetAsync(hist, 0, hist_bytes, stream);
  hist_kernel<<<(BATCH * NPIX) / 1024, 1024, 0, stream>>>(in, out, hist);
  scan_kernel<<<BATCH, 1024, 0, stream>>>(hist, off, cur);
  scatter_kernel<<<(BATCH * NPIX) / 1024, 1024, 0, stream>>>(in, cur, emb, pk);
  cluster_kernel<<<BATCH, 1024, 0, stream>>>(in, out, emb, pk, off);
}